// Round 1
// baseline (511.265 us; speedup 1.0000x reference)
//
#include <hip/hip_runtime.h>
#include <hip/hip_bf16.h>

#define Bn 16
#define Sn 512
#define Hn 768
#define Ln 4096

typedef __attribute__((ext_vector_type(8))) short bf16x8;
typedef __attribute__((ext_vector_type(4))) float f32x4;

using bf16 = __hip_bfloat16;

constexpr int BL = 64;   // l-rows per block

// ---- LDS layout (time-multiplexed, offsets in bytes) ----
// phase2:  double-buffered {Xs [512][64B] + Ws [64][64B]} = 36864 per buf, 2 bufs
//          16B chunks XOR-swizzled: slot = chunk ^ (row&3)  (rows are 64B = 4 chunks)
// softmax: redm[4][64] f32 @ 73728, reds[4][64] f32 @ 74752
// phase5:  P  [64 rows][1024 B] @ 0      16B chunks swizzled: slot = chunk ^ (row&7)
//          XT [128 rows][128 B] @ 65536  chunks swizzled same way
constexpr int SM_BYTES = 81920;  // 2 blocks/CU
constexpr int PH2_BUF  = 36864;
constexpr int P_OFF    = 0;
constexpr int XT_OFF   = 65536;
constexpr int REDM_OFF = 73728;
constexpr int REDS_OFF = 74752;

typedef const __attribute__((address_space(1))) unsigned int* gas_ptr;
typedef __attribute__((address_space(3))) unsigned int* las_ptr;

__device__ __forceinline__ void gld_lds16(const void* g, void* l) {
  // async 16B/lane global->LDS DMA; LDS dest = wave-uniform base + lane*16
  __builtin_amdgcn_global_load_lds((gas_ptr)g, (las_ptr)l, 16, 0, 0);
}

__device__ __forceinline__ unsigned short bfbits(float x) {
  __hip_bfloat16 h = __float2bfloat16(x);
  unsigned short u;
  __builtin_memcpy(&u, &h, 2);
  return u;
}

union Pack8 { bf16 h[8]; uint4 u; };

__device__ inline uint4 cvt8(float4 a, float4 b) {
  Pack8 p;
  p.h[0] = __float2bfloat16(a.x); p.h[1] = __float2bfloat16(a.y);
  p.h[2] = __float2bfloat16(a.z); p.h[3] = __float2bfloat16(a.w);
  p.h[4] = __float2bfloat16(b.x); p.h[5] = __float2bfloat16(b.y);
  p.h[6] = __float2bfloat16(b.z); p.h[7] = __float2bfloat16(b.w);
  return p.u;
}

// ---- pre-kernel: X fp32 -> bf16 row-major AND bf16 transposed [B][H][S] ----
__global__ __launch_bounds__(256) void convert_x_kernel(
    const float* __restrict__ X, bf16* __restrict__ Xbf, bf16* __restrict__ XT) {
  __shared__ bf16 t[64][72];
  const int tid = threadIdx.x;
  const int b  = blockIdx.z;
  const int s0 = blockIdx.y * 64;
  const int h0 = blockIdx.x * 64;
  const int r = tid >> 2;
  const int p = tid & 3;
  const float* src = X + ((size_t)b * Sn + s0 + r) * Hn + h0 + p * 16;
  float4 a0 = *(const float4*)(src + 0);
  float4 a1 = *(const float4*)(src + 4);
  float4 a2 = *(const float4*)(src + 8);
  float4 a3 = *(const float4*)(src + 12);
  uint4 u0 = cvt8(a0, a1);
  uint4 u1 = cvt8(a2, a3);
  bf16* xb = Xbf + ((size_t)b * Sn + s0 + r) * Hn + h0 + p * 16;
  *(uint4*)(xb)     = u0;
  *(uint4*)(xb + 8) = u1;
  *(uint4*)&t[r][p * 16]     = u0;
  *(uint4*)&t[r][p * 16 + 8] = u1;
  __syncthreads();
  Pack8 o0, o1;
#pragma unroll
  for (int i = 0; i < 8; ++i) {
    o0.h[i] = t[p * 16 + i][r];
    o1.h[i] = t[p * 16 + 8 + i][r];
  }
  bf16* xt = XT + ((size_t)b * Hn + h0 + r) * Sn + s0 + p * 16;
  *(uint4*)(xt)     = o0.u;
  *(uint4*)(xt + 8) = o1.u;
}

// ---- pre-kernel: W fp32 -> bf16 ----
__global__ __launch_bounds__(256) void convert_w_kernel(
    const float* __restrict__ W, bf16* __restrict__ Wbf) {
  const size_t i = ((size_t)blockIdx.x * 256 + threadIdx.x) * 8;
  float4 a0 = *(const float4*)(W + i);
  float4 a1 = *(const float4*)(W + i + 4);
  *(uint4*)(Wbf + i) = cvt8(a0, a1);
}

// ---- fused main kernel ----
// phase2: wave w owns s-slice [w*128, w*128+128); tile M=64 (all l) x N=128.
// phase5: wave w: lg = w>>1 owns l rows lg*32..+31; sg = w&1 owns nt-parity of 128-h chunk.
__global__ __launch_bounds__(256, 2) void attn_main_kernel(
    const int* __restrict__ masks,
    const bf16* __restrict__ Xbf, const bf16* __restrict__ XTg,
    const bf16* __restrict__ Wbf, float* __restrict__ out) {
  __shared__ char sm[SM_BYTES];
  const int tid  = threadIdx.x;
  const int w    = tid >> 6;
  const int lane = tid & 63;
  const int col  = lane & 15;
  const int quad = lane >> 4;
  const int lg   = w >> 1;
  const int sg   = w & 1;
  // XCD-aware swizzle: 1024 blocks = 8 XCDs x 128; groups each batch's X/XT
  // working set (~3.1 MB) into one XCD's L2.
  const int vb = (blockIdx.x & 7) * 128 + (blockIdx.x >> 3);
  const int b  = vb >> 6;
  const int l0 = (vb & 63) * BL;

  // mask bias -> 8 regs (this lane's 8 s-columns within the wave's 128-slice)
  float bias_r[8];
  {
    const int* mrow = masks + b * Sn + w * 128 + col;
#pragma unroll
    for (int nt = 0; nt < 8; ++nt)
      bias_r[nt] = mrow[nt * 16] ? 0.0f : -1e30f;
  }

  const f32x4 zero = {0.f, 0.f, 0.f, 0.f};
  f32x4 acc[4][8];
#pragma unroll
  for (int a = 0; a < 4; ++a)
#pragma unroll
    for (int nt = 0; nt < 8; ++nt) acc[a][nt] = zero;

  // staging coords (16 rows x 4 chunks per gld_lds16); source-side XOR swizzle
  // so LDS chunk slot c of row r holds global chunk c^(r&3).
  const int rr2 = lane >> 2;
  const int cc2 = lane & 3;
  const int swk = (cc2 ^ (rr2 & 3)) * 8;  // element offset into k

  auto stage2 = [&](int p, int k0) {
    // Xs: wave stages its own compute rows w*128..+127 (8 insts x 16 rows x 64B)
    const bf16* gx = Xbf + ((size_t)b * Sn + w * 128 + rr2) * Hn + k0 + swk;
    char* dx = sm + p * PH2_BUF + (w * 128) * 64;
#pragma unroll
    for (int i = 0; i < 8; ++i) {
      gld_lds16(gx, dx);
      gx += 16 * Hn;
      dx += 16 * 64;
    }
    // Ws: wave stages rows w*16..+15
    const bf16* gw = Wbf + ((size_t)(l0 + w * 16 + rr2)) * Hn + k0 + swk;
    gld_lds16(gw, sm + p * PH2_BUF + 32768 + (w * 16) * 64);
  };

  // ---- phase 2: scores[64l x 512s]; proper 2-phase dbuf pipeline ----
  stage2(0, 0);
  __syncthreads();
  int p = 0;
  const int swr = (quad ^ (col & 3)) * 16;  // read-side chunk swizzle
  for (int k0 = 0; k0 < Hn; k0 += 32) {
    if (k0 + 32 < Hn) stage2(p ^ 1, k0 + 32);  // issue next BEFORE compute
    const char* xs = sm + p * PH2_BUF;
    const char* ws = sm + p * PH2_BUF + 32768;
    bf16x8 aF[4], bF[8];
#pragma unroll
    for (int a = 0; a < 4; ++a)
      aF[a] = *(const bf16x8*)(ws + (a * 16 + col) * 64 + swr);
#pragma unroll
    for (int nt = 0; nt < 8; ++nt)
      bF[nt] = *(const bf16x8*)(xs + (w * 128 + nt * 16 + col) * 64 + swr);
#pragma unroll
    for (int nt = 0; nt < 8; ++nt)
#pragma unroll
      for (int a = 0; a < 4; ++a)
        acc[a][nt] = __builtin_amdgcn_mfma_f32_16x16x32_bf16(aF[a], bF[nt], acc[a][nt], 0, 0, 0);
    __syncthreads();  // single drain per iter (vmcnt covers prefetch issued ~compute earlier)
    p ^= 1;
  }

  // ---- phase 3: masked softmax, 4-way cross-wave combine over s-slices ----
  float* redm = (float*)&sm[REDM_OFF];
  float* reds = (float*)&sm[REDS_OFF];
  float mx[4][4];
#pragma unroll
  for (int a = 0; a < 4; ++a)
#pragma unroll
    for (int r = 0; r < 4; ++r) mx[a][r] = -3e38f;
#pragma unroll
  for (int a = 0; a < 4; ++a)
#pragma unroll
    for (int nt = 0; nt < 8; ++nt)
#pragma unroll
      for (int r = 0; r < 4; ++r) {
        acc[a][nt][r] += bias_r[nt];
        mx[a][r] = fmaxf(mx[a][r], acc[a][nt][r]);
      }
#pragma unroll
  for (int a = 0; a < 4; ++a)
#pragma unroll
    for (int r = 0; r < 4; ++r) {
      mx[a][r] = fmaxf(mx[a][r], __shfl_xor(mx[a][r], 1, 64));
      mx[a][r] = fmaxf(mx[a][r], __shfl_xor(mx[a][r], 2, 64));
      mx[a][r] = fmaxf(mx[a][r], __shfl_xor(mx[a][r], 4, 64));
      mx[a][r] = fmaxf(mx[a][r], __shfl_xor(mx[a][r], 8, 64));
    }
  if (col == 0) {
#pragma unroll
    for (int a = 0; a < 4; ++a)
#pragma unroll
      for (int r = 0; r < 4; ++r)
        redm[w * 64 + a * 16 + quad * 4 + r] = mx[a][r];
  }
  __syncthreads();
  float gmax[4][4], sum[4][4];
#pragma unroll
  for (int a = 0; a < 4; ++a)
#pragma unroll
    for (int r = 0; r < 4; ++r) {
      const int row = a * 16 + quad * 4 + r;
      gmax[a][r] = fmaxf(fmaxf(redm[row], redm[64 + row]),
                         fmaxf(redm[128 + row], redm[192 + row]));
      sum[a][r] = 0.f;
    }
#pragma unroll
  for (int a = 0; a < 4; ++a)
#pragma unroll
    for (int nt = 0; nt < 8; ++nt)
#pragma unroll
      for (int r = 0; r < 4; ++r) {
        const float e = __expf(acc[a][nt][r] - gmax[a][r]);
        acc[a][nt][r] = e;
        sum[a][r] += e;
      }
#pragma unroll
  for (int a = 0; a < 4; ++a)
#pragma unroll
    for (int r = 0; r < 4; ++r) {
      sum[a][r] += __shfl_xor(sum[a][r], 1, 64);
      sum[a][r] += __shfl_xor(sum[a][r], 2, 64);
      sum[a][r] += __shfl_xor(sum[a][r], 4, 64);
      sum[a][r] += __shfl_xor(sum[a][r], 8, 64);
    }
  if (col == 0) {
#pragma unroll
    for (int a = 0; a < 4; ++a)
#pragma unroll
      for (int r = 0; r < 4; ++r)
        reds[w * 64 + a * 16 + quad * 4 + r] = sum[a][r];
  }
  __syncthreads();
  float rs[4][4];
#pragma unroll
  for (int a = 0; a < 4; ++a)
#pragma unroll
    for (int r = 0; r < 4; ++r) {
      const int row = a * 16 + quad * 4 + r;
      rs[a][r] = 1.0f / (reds[row] + reds[64 + row] + reds[128 + row] + reds[192 + row]);
    }

  // ---- phase 5 prologue: issue first XT tile loads (T14: global -> regs) ----
  const int rr5 = lane >> 3;   // 0..7
  const int cc5 = lane & 7;    // chunk within 128B row
  uint4 xtr[4];
  auto load_xt = [&](int n0, int s0) {
    // coalesced: 8 lanes read 128B contiguous per row; 8 rows per inst group
    const bf16* g = XTg + ((size_t)b * Hn + n0 * 128 + w * 32 + rr5) * Sn + s0 + cc5 * 8;
#pragma unroll
    for (int i = 0; i < 4; ++i) {
      xtr[i] = *(const uint4*)g;
      g += 8 * Sn;
    }
  };
  load_xt(0, 0);

  // ---- phase 4: P (unnormalized exp) -> LDS bf16, b32 packed via shfl pairing ----
  // P row = 1024 B (512 bf16). 16B chunk c of row stored at slot c ^ (row&7).
  const int pi = col & 1;  // parity
#pragma unroll
  for (int a = 0; a < 4; ++a)
#pragma unroll
    for (int t = 0; t < 4; ++t)
#pragma unroll
      for (int r = 0; r < 4; ++r) {
        const float own0 = acc[a][2 * t][r];
        const float own1 = acc[a][2 * t + 1][r];
        const float p0 = __shfl_xor(own0, 1, 64);
        const float p1 = __shfl_xor(own1, 1, 64);
        const float lo = pi ? p1 : own0;
        const float hi = pi ? own1 : p0;
        const unsigned pk = (unsigned)bfbits(lo) | ((unsigned)bfbits(hi) << 16);
        const int nt_w = 2 * t + pi;
        const int row = a * 16 + quad * 4 + r;
        const int sp = w * 128 + nt_w * 16 + (col & ~1);
        const int slot = (sp >> 3) ^ (row & 7);
        *(unsigned*)&sm[P_OFF + row * 1024 + slot * 16 + (sp & 7) * 2] = pk;
      }

  // ---- phase 5: O[64l x 768h] = P[64,512] x X[512,768]; T14 reg-staged XT ----
  for (int n0 = 0; n0 < Hn / 128; ++n0) {
    f32x4 oacc[2][4];
#pragma unroll
    for (int a = 0; a < 2; ++a)
#pragma unroll
      for (int nt = 0; nt < 4; ++nt) oacc[a][nt] = zero;
    for (int s0 = 0; s0 < Sn; s0 += 64) {
      __syncthreads();  // (1) prev tile consumed by all; implicit vmcnt(0): xtr arrived
      // swizzled ds_write: LDS slot (cc^rr) of row holds global chunk cc -> chunk c at slot c^(row&7)
#pragma unroll
      for (int i = 0; i < 4; ++i)
        *(uint4*)&sm[XT_OFF + (w * 32 + i * 8 + rr5) * 128 + ((cc5 ^ rr5) * 16)] = xtr[i];
      __syncthreads();  // (2) tile visible
      // issue NEXT tile loads now: 16 MFMAs below hide the latency; drained at next (1)
      if (!((n0 == Hn / 128 - 1) && (s0 + 64 == Sn))) {
        int ns0 = s0 + 64, nn0 = n0;
        if (ns0 == Sn) { ns0 = 0; ++nn0; }
        load_xt(nn0, ns0);
      }
#pragma unroll
      for (int ks = 0; ks < 2; ++ks) {
        const int chunk = (s0 + ks * 32 + quad * 8) >> 3;
        bf16x8 pa[2];
#pragma unroll
        for (int a = 0; a < 2; ++a) {
          const int row = lg * 32 + a * 16 + col;
          const int slot = chunk ^ (row & 7);
          pa[a] = *(const bf16x8*)&sm[P_OFF + row * 1024 + slot * 16];
        }
#pragma unroll
        for (int nt = 0; nt < 4; ++nt) {
          const int hl = (nt * 2 + sg) * 16 + col;
          const int xslot = (ks * 4 + quad) ^ (hl & 7);
          bf16x8 xb = *(const bf16x8*)&sm[XT_OFF + hl * 128 + xslot * 16];
          oacc[0][nt] = __builtin_amdgcn_mfma_f32_16x16x32_bf16(pa[0], xb, oacc[0][nt], 0, 0, 0);
          oacc[1][nt] = __builtin_amdgcn_mfma_f32_16x16x32_bf16(pa[1], xb, oacc[1][nt], 0, 0, 0);
        }
      }
    }
#pragma unroll
    for (int a = 0; a < 2; ++a)
#pragma unroll
      for (int nt = 0; nt < 4; ++nt) {
        const int h = n0 * 128 + (nt * 2 + sg) * 16 + col;
        const int lbase = l0 + lg * 32 + a * 16 + quad * 4;
#pragma unroll
        for (int r = 0; r < 4; ++r)
          out[((size_t)b * Ln + lbase + r) * Hn + h] = oacc[a][nt][r] * rs[lg * 2 + a][r];
      }
  }
}

// ---- fallback (ws too small): fp32 wave-per-(b,l), slow but correct ----
__global__ __launch_bounds__(256) void attn_fallback_kernel(
    const float* __restrict__ X, const int* __restrict__ masks,
    const float* __restrict__ W, float* __restrict__ out) {
  __shared__ float sc[4][Sn];
  const int wv = threadIdx.x >> 6, lane = threadIdx.x & 63;
  const int gw = blockIdx.x * 4 + wv;
  const int b = gw / Ln, l = gw % Ln;
  float wreg[12];
#pragma unroll
  for (int j = 0; j < 12; ++j) wreg[j] = W[(size_t)l * Hn + j * 64 + lane];
  for (int s = 0; s < Sn; ++s) {
    const float* xr = X + ((size_t)b * Sn + s) * Hn;
    float p = 0.f;
#pragma unroll
    for (int j = 0; j < 12; ++j) p += xr[j * 64 + lane] * wreg[j];
#pragma unroll
    for (int off = 32; off > 0; off >>= 1) p += __shfl_xor(p, off, 64);
    if (lane == 0) sc[wv][s] = p;
  }
  __syncthreads();
  float m = -3e38f;
#pragma unroll
  for (int i = 0; i < 8; ++i) {
    const int s = lane * 8 + i;
    const float v = sc[wv][s] + (masks[b * Sn + s] ? 0.f : -1e30f);
    sc[wv][s] = v;
    m = fmaxf(m, v);
  }
#pragma unroll
  for (int off = 32; off > 0; off >>= 1) m = fmaxf(m, __shfl_xor(m, off, 64));
  __syncthreads();
  float sum = 0.f;
#pragma unroll
  for (int i = 0; i < 8; ++i) {
    const int s = lane * 8 + i;
    const float e = __expf(sc[wv][s] - m);
    sc[wv][s] = e;
    sum += e;
  }
#pragma unroll
  for (int off = 32; off > 0; off >>= 1) sum += __shfl_xor(sum, off, 64);
  const float rs = 1.0f / sum;
  __syncthreads();
  float o[12];
#pragma unroll
  for (int j = 0; j < 12; ++j) o[j] = 0.f;
  for (int s = 0; s < Sn; ++s) {
    const float p = sc[wv][s];
    const float* xr = X + ((size_t)b * Sn + s) * Hn;
#pragma unroll
    for (int j = 0; j < 12; ++j) o[j] += p * xr[j * 64 + lane];
  }
#pragma unroll
  for (int j = 0; j < 12; ++j)
    out[((size_t)b * Ln + l) * Hn + j * 64 + lane] = o[j] * rs;
}

extern "C" void kernel_launch(void* const* d_in, const int* in_sizes, int n_in,
                              void* d_out, int out_size, void* d_ws, size_t ws_size,
                              hipStream_t stream) {
  const float* X     = (const float*)d_in[0];
  const int*   masks = (const int*)d_in[1];
  const float* W     = (const float*)d_in[2];
  float* out = (float*)d_out;

  const size_t need = ((size_t)2 * Bn * Sn * Hn + (size_t)Ln * Hn) * sizeof(bf16);
  if (ws_size >= need) {
    bf16* Xbf = (bf16*)d_ws;
    bf16* XT  = Xbf + (size_t)Bn * Sn * Hn;
    bf16* Wbf = XT  + (size_t)Bn * Sn * Hn;
    convert_x_kernel<<<dim3(Hn / 64, Sn / 64, Bn), 256, 0, stream>>>(X, Xbf, XT);
    convert_w_kernel<<<dim3((Ln * Hn) / 2048), 256, 0, stream>>>(W, Wbf);
    attn_main_kernel<<<dim3(Bn * (Ln / BL)), 256, 0, stream>>>(masks, Xbf, XT, Wbf, out);
  } else {
    attn_fallback_kernel<<<dim3(Bn * Ln / 4), 256, 0, stream>>>(X, masks, W, out);
  }
}

// Round 2
// 474.470 us; speedup vs baseline: 1.0775x; 1.0775x over previous
//
#include <hip/hip_runtime.h>
#include <hip/hip_bf16.h>

#define Bn 16
#define Sn 512
#define Hn 768
#define Ln 4096

typedef __attribute__((ext_vector_type(8))) short bf16x8;
typedef __attribute__((ext_vector_type(4))) float f32x4;

using bf16 = __hip_bfloat16;

constexpr int BL = 64;   // l-rows per block

// ---- LDS layout (time-multiplexed, offsets in bytes) ----
// phase2:  Xs [512 rows][64 B]    @ 0       (32768)  row = s, 32 k bf16
//          Ws [ 64 rows][64 B]    @ 32768   (4096)   row = l-local
// softmax: redm[2][64] f32        @ 65536   (512)
//          reds[2][64] f32        @ 66048   (512)
// phase5:  P  [64 rows][1024 B]   @ 0       (65536)  16B chunks XOR-swizzled: slot = chunk ^ (row&7)
//          (XT is NOT staged: B-operand read directly from L2-resident XT)
constexpr int SM_BYTES = 66560;  // 2 blocks/CU (133 KiB of 160)
constexpr int XS_OFF   = 0;
constexpr int WS_OFF   = 32768;
constexpr int P_OFF    = 0;
constexpr int REDM_OFF = 65536;
constexpr int REDS_OFF = 66048;

typedef const __attribute__((address_space(1))) unsigned int* gas_ptr;
typedef __attribute__((address_space(3))) unsigned int* las_ptr;

__device__ __forceinline__ void gld_lds16(const void* g, void* l) {
  // async 16B/lane global->LDS DMA; LDS dest = wave-uniform base + lane*16
  __builtin_amdgcn_global_load_lds((gas_ptr)g, (las_ptr)l, 16, 0, 0);
}

__device__ __forceinline__ unsigned short bfbits(float x) {
  __hip_bfloat16 h = __float2bfloat16(x);
  unsigned short u;
  __builtin_memcpy(&u, &h, 2);
  return u;
}

union Pack8 { bf16 h[8]; uint4 u; };

__device__ inline uint4 cvt8(float4 a, float4 b) {
  Pack8 p;
  p.h[0] = __float2bfloat16(a.x); p.h[1] = __float2bfloat16(a.y);
  p.h[2] = __float2bfloat16(a.z); p.h[3] = __float2bfloat16(a.w);
  p.h[4] = __float2bfloat16(b.x); p.h[5] = __float2bfloat16(b.y);
  p.h[6] = __float2bfloat16(b.z); p.h[7] = __float2bfloat16(b.w);
  return p.u;
}

// ---- pre-kernel: X fp32 -> bf16 row-major AND bf16 transposed [B][H][S] ----
__global__ __launch_bounds__(256) void convert_x_kernel(
    const float* __restrict__ X, bf16* __restrict__ Xbf, bf16* __restrict__ XT) {
  __shared__ bf16 t[64][72];
  const int tid = threadIdx.x;
  const int b  = blockIdx.z;
  const int s0 = blockIdx.y * 64;
  const int h0 = blockIdx.x * 64;
  const int r = tid >> 2;
  const int p = tid & 3;
  const float* src = X + ((size_t)b * Sn + s0 + r) * Hn + h0 + p * 16;
  float4 a0 = *(const float4*)(src + 0);
  float4 a1 = *(const float4*)(src + 4);
  float4 a2 = *(const float4*)(src + 8);
  float4 a3 = *(const float4*)(src + 12);
  uint4 u0 = cvt8(a0, a1);
  uint4 u1 = cvt8(a2, a3);
  bf16* xb = Xbf + ((size_t)b * Sn + s0 + r) * Hn + h0 + p * 16;
  *(uint4*)(xb)     = u0;
  *(uint4*)(xb + 8) = u1;
  *(uint4*)&t[r][p * 16]     = u0;
  *(uint4*)&t[r][p * 16 + 8] = u1;
  __syncthreads();
  Pack8 o0, o1;
#pragma unroll
  for (int i = 0; i < 8; ++i) {
    o0.h[i] = t[p * 16 + i][r];
    o1.h[i] = t[p * 16 + 8 + i][r];
  }
  bf16* xt = XT + ((size_t)b * Hn + h0 + r) * Sn + s0 + p * 16;
  *(uint4*)(xt)     = o0.u;
  *(uint4*)(xt + 8) = o1.u;
}

// ---- pre-kernel: W fp32 -> bf16 ----
__global__ __launch_bounds__(256) void convert_w_kernel(
    const float* __restrict__ W, bf16* __restrict__ Wbf) {
  const size_t i = ((size_t)blockIdx.x * 256 + threadIdx.x) * 8;
  float4 a0 = *(const float4*)(W + i);
  float4 a1 = *(const float4*)(W + i + 4);
  *(uint4*)(Wbf + i) = cvt8(a0, a1);
}

// ---- fused main kernel ----
// wave w: lg = w>>1 owns l rows lg*32..+31; sg = w&1 owns s half sg*256..+255 (phase2)
//         and nt-parity sg of each 128-h chunk (phase5)
__global__ __launch_bounds__(256, 2) void attn_main_kernel(
    const int* __restrict__ masks,
    const bf16* __restrict__ Xbf, const bf16* __restrict__ XTg,
    const bf16* __restrict__ Wbf, float* __restrict__ out) {
  __shared__ char sm[SM_BYTES];
  const int tid  = threadIdx.x;
  const int w    = tid >> 6;
  const int lane = tid & 63;
  const int col  = lane & 15;
  const int quad = lane >> 4;
  const int lg   = w >> 1;
  const int sg   = w & 1;
  // XCD-aware swizzle: 1024 blocks = 8 XCDs x 128. Each XCD's resident blocks
  // share one batch b -> X/XT (1.5 MB) + W slices stay L2-resident.
  const int vb = (blockIdx.x & 7) * 128 + (blockIdx.x >> 3);
  const int b  = vb >> 6;
  const int l0 = (vb & 63) * BL;

  // mask bias -> 16 regs (this lane's 16 s-columns within its half)
  float bias_r[16];
  {
    const int* mrow = masks + b * Sn + sg * 256 + col;
#pragma unroll
    for (int nt = 0; nt < 16; ++nt)
      bias_r[nt] = mrow[nt * 16] ? 0.0f : -1e30f;
  }

  const f32x4 zero = {0.f, 0.f, 0.f, 0.f};
  f32x4 acc[2][16];
#pragma unroll
  for (int a = 0; a < 2; ++a)
#pragma unroll
    for (int nt = 0; nt < 16; ++nt) acc[a][nt] = zero;

  // ---- phase 2: scores[64l x 512s]; wave computes 32l x 256s ----
  for (int k0 = 0; k0 < Hn; k0 += 32) {
    __syncthreads();
    {
      // Xs: wave stages rows w*128..+127 (8 insts x 16 rows x 64B)
      const int r0 = w * 128;
      const bf16* g = Xbf + ((size_t)b * Sn + r0 + (lane >> 2)) * Hn + k0 + (lane & 3) * 8;
#pragma unroll
      for (int i = 0; i < 8; ++i) {
        gld_lds16(g, &sm[XS_OFF + (r0 + i * 16) * 64]);
        g += 16 * Hn;
      }
      // Ws: wave stages rows w*16..+15
      const bf16* gw = Wbf + ((size_t)(l0 + w * 16 + (lane >> 2))) * Hn + k0 + (lane & 3) * 8;
      gld_lds16(gw, &sm[WS_OFF + (w * 16) * 64]);
    }
    __syncthreads();
    bf16x8 a0 = *(const bf16x8*)&sm[WS_OFF + (lg * 32 + col) * 64 + quad * 16];
    bf16x8 a1 = *(const bf16x8*)&sm[WS_OFF + (lg * 32 + 16 + col) * 64 + quad * 16];
#pragma unroll
    for (int nt = 0; nt < 16; ++nt) {
      bf16x8 bf_ = *(const bf16x8*)&sm[XS_OFF + (sg * 256 + nt * 16 + col) * 64 + quad * 16];
      acc[0][nt] = __builtin_amdgcn_mfma_f32_16x16x32_bf16(a0, bf_, acc[0][nt], 0, 0, 0);
      acc[1][nt] = __builtin_amdgcn_mfma_f32_16x16x32_bf16(a1, bf_, acc[1][nt], 0, 0, 0);
    }
  }

  // ---- phase 3: masked softmax, cross-wave (s split over sg) ----
  float* redm = (float*)&sm[REDM_OFF];
  float* reds = (float*)&sm[REDS_OFF];
  float mx[2][4];
#pragma unroll
  for (int a = 0; a < 2; ++a)
#pragma unroll
    for (int r = 0; r < 4; ++r) mx[a][r] = -3e38f;
#pragma unroll
  for (int a = 0; a < 2; ++a)
#pragma unroll
    for (int nt = 0; nt < 16; ++nt)
#pragma unroll
      for (int r = 0; r < 4; ++r) {
        acc[a][nt][r] += bias_r[nt];
        mx[a][r] = fmaxf(mx[a][r], acc[a][nt][r]);
      }
#pragma unroll
  for (int a = 0; a < 2; ++a)
#pragma unroll
    for (int r = 0; r < 4; ++r) {
      mx[a][r] = fmaxf(mx[a][r], __shfl_xor(mx[a][r], 1, 64));
      mx[a][r] = fmaxf(mx[a][r], __shfl_xor(mx[a][r], 2, 64));
      mx[a][r] = fmaxf(mx[a][r], __shfl_xor(mx[a][r], 4, 64));
      mx[a][r] = fmaxf(mx[a][r], __shfl_xor(mx[a][r], 8, 64));
    }
  if (col == 0) {
#pragma unroll
    for (int a = 0; a < 2; ++a)
#pragma unroll
      for (int r = 0; r < 4; ++r)
        redm[sg * 64 + lg * 32 + a * 16 + quad * 4 + r] = mx[a][r];
  }
  __syncthreads();
  float gmax[2][4], sum[2][4];
#pragma unroll
  for (int a = 0; a < 2; ++a)
#pragma unroll
    for (int r = 0; r < 4; ++r) {
      const int row = lg * 32 + a * 16 + quad * 4 + r;
      gmax[a][r] = fmaxf(redm[row], redm[64 + row]);
      sum[a][r] = 0.f;
    }
#pragma unroll
  for (int a = 0; a < 2; ++a)
#pragma unroll
    for (int nt = 0; nt < 16; ++nt)
#pragma unroll
      for (int r = 0; r < 4; ++r) {
        const float e = __expf(acc[a][nt][r] - gmax[a][r]);
        acc[a][nt][r] = e;
        sum[a][r] += e;
      }
#pragma unroll
  for (int a = 0; a < 2; ++a)
#pragma unroll
    for (int r = 0; r < 4; ++r) {
      sum[a][r] += __shfl_xor(sum[a][r], 1, 64);
      sum[a][r] += __shfl_xor(sum[a][r], 2, 64);
      sum[a][r] += __shfl_xor(sum[a][r], 4, 64);
      sum[a][r] += __shfl_xor(sum[a][r], 8, 64);
    }
  if (col == 0) {
#pragma unroll
    for (int a = 0; a < 2; ++a)
#pragma unroll
      for (int r = 0; r < 4; ++r)
        reds[sg * 64 + lg * 32 + a * 16 + quad * 4 + r] = sum[a][r];
  }
  __syncthreads();
  float rs[2][4];
#pragma unroll
  for (int a = 0; a < 2; ++a)
#pragma unroll
    for (int r = 0; r < 4; ++r) {
      const int row = lg * 32 + a * 16 + quad * 4 + r;
      rs[a][r] = 1.0f / (reds[row] + reds[64 + row]);
    }

  // ---- phase 4: P (unnormalized exp) -> LDS bf16, b32 packed via shfl pairing ----
  // P row = 1024 B (512 bf16). 16B chunk c of row stored at slot c ^ (row&7).
  const int pi = col & 1;  // parity
#pragma unroll
  for (int a = 0; a < 2; ++a)
#pragma unroll
    for (int t = 0; t < 8; ++t)
#pragma unroll
      for (int r = 0; r < 4; ++r) {
        const float own0 = acc[a][2 * t][r];
        const float own1 = acc[a][2 * t + 1][r];
        const float p0 = __shfl_xor(own0, 1, 64);  // partner's nt=2t value
        const float p1 = __shfl_xor(own1, 1, 64);  // partner's nt=2t+1 value
        const float lo = pi ? p1 : own0;
        const float hi = pi ? own1 : p0;
        const unsigned pk = (unsigned)bfbits(lo) | ((unsigned)bfbits(hi) << 16);
        const int nt_w = 2 * t + pi;
        const int row = lg * 32 + a * 16 + quad * 4 + r;
        const int sp = sg * 256 + nt_w * 16 + (col & ~1);
        const int slot = (sp >> 3) ^ (row & 7);
        *(unsigned*)&sm[P_OFF + row * 1024 + slot * 16 + (sp & 7) * 2] = pk;
      }

  __syncthreads();  // P visible; no further barriers (phase 5 is barrier-free)

  // ---- phase 5: O[64l x 768h] = P[64,512] x X[512,768] ----
  // B-operand (XT) is read DIRECTLY from global: XT[b] = 768 KB, L2-resident
  // (XCD swizzle keeps one b per XCD). No staging, no barriers -> resident
  // waves hide L2 latency; saves 96 barriers + all XT LDS traffic.
  const bf16* xtb = XTg + (size_t)b * Hn * Sn;
  for (int n0 = 0; n0 < Hn / 128; ++n0) {
    f32x4 oacc[2][4];
#pragma unroll
    for (int a = 0; a < 2; ++a)
#pragma unroll
      for (int nt = 0; nt < 4; ++nt) oacc[a][nt] = zero;
#pragma unroll 2
    for (int s0 = 0; s0 < Sn; s0 += 64) {
#pragma unroll
      for (int ks = 0; ks < 2; ++ks) {
        const int chunk = (s0 + ks * 32 + quad * 8) >> 3;
        bf16x8 pa[2];
#pragma unroll
        for (int a = 0; a < 2; ++a) {
          const int row = lg * 32 + a * 16 + col;
          const int slot = chunk ^ (row & 7);
          pa[a] = *(const bf16x8*)&sm[P_OFF + row * 1024 + slot * 16];
        }
#pragma unroll
        for (int nt = 0; nt < 4; ++nt) {
          const int hl = (nt * 2 + sg) * 16 + col;
          // 4 quads read 4x16B = one 64B segment per h-row: fully-used L2 lines
          bf16x8 xb = *(const bf16x8*)(xtb + ((size_t)(n0 * 128 + hl)) * Sn + s0 + ks * 32 + quad * 8);
          oacc[0][nt] = __builtin_amdgcn_mfma_f32_16x16x32_bf16(pa[0], xb, oacc[0][nt], 0, 0, 0);
          oacc[1][nt] = __builtin_amdgcn_mfma_f32_16x16x32_bf16(pa[1], xb, oacc[1][nt], 0, 0, 0);
        }
      }
    }
#pragma unroll
    for (int a = 0; a < 2; ++a)
#pragma unroll
      for (int nt = 0; nt < 4; ++nt) {
        const int h = n0 * 128 + (nt * 2 + sg) * 16 + col;
        const int lbase = l0 + lg * 32 + a * 16 + quad * 4;
#pragma unroll
        for (int r = 0; r < 4; ++r)
          out[((size_t)b * Ln + lbase + r) * Hn + h] = oacc[a][nt][r] * rs[a][r];
      }
  }
}

// ---- fallback (ws too small): fp32 wave-per-(b,l), slow but correct ----
__global__ __launch_bounds__(256) void attn_fallback_kernel(
    const float* __restrict__ X, const int* __restrict__ masks,
    const float* __restrict__ W, float* __restrict__ out) {
  __shared__ float sc[4][Sn];
  const int wv = threadIdx.x >> 6, lane = threadIdx.x & 63;
  const int gw = blockIdx.x * 4 + wv;
  const int b = gw / Ln, l = gw % Ln;
  float wreg[12];
#pragma unroll
  for (int j = 0; j < 12; ++j) wreg[j] = W[(size_t)l * Hn + j * 64 + lane];
  for (int s = 0; s < Sn; ++s) {
    const float* xr = X + ((size_t)b * Sn + s) * Hn;
    float p = 0.f;
#pragma unroll
    for (int j = 0; j < 12; ++j) p += xr[j * 64 + lane] * wreg[j];
#pragma unroll
    for (int off = 32; off > 0; off >>= 1) p += __shfl_xor(p, off, 64);
    if (lane == 0) sc[wv][s] = p;
  }
  __syncthreads();
  float m = -3e38f;
#pragma unroll
  for (int i = 0; i < 8; ++i) {
    const int s = lane * 8 + i;
    const float v = sc[wv][s] + (masks[b * Sn + s] ? 0.f : -1e30f);
    sc[wv][s] = v;
    m = fmaxf(m, v);
  }
#pragma unroll
  for (int off = 32; off > 0; off >>= 1) m = fmaxf(m, __shfl_xor(m, off, 64));
  __syncthreads();
  float sum = 0.f;
#pragma unroll
  for (int i = 0; i < 8; ++i) {
    const int s = lane * 8 + i;
    const float e = __expf(sc[wv][s] - m);
    sc[wv][s] = e;
    sum += e;
  }
#pragma unroll
  for (int off = 32; off > 0; off >>= 1) sum += __shfl_xor(sum, off, 64);
  const float rs = 1.0f / sum;
  __syncthreads();
  float o[12];
#pragma unroll
  for (int j = 0; j < 12; ++j) o[j] = 0.f;
  for (int s = 0; s < Sn; ++s) {
    const float p = sc[wv][s];
    const float* xr = X + ((size_t)b * Sn + s) * Hn;
#pragma unroll
    for (int j = 0; j < 12; ++j) o[j] += p * xr[j * 64 + lane];
  }
#pragma unroll
  for (int j = 0; j < 12; ++j)
    out[((size_t)b * Ln + l) * Hn + j * 64 + lane] = o[j] * rs;
}

extern "C" void kernel_launch(void* const* d_in, const int* in_sizes, int n_in,
                              void* d_out, int out_size, void* d_ws, size_t ws_size,
                              hipStream_t stream) {
  const float* X     = (const float*)d_in[0];
  const int*   masks = (const int*)d_in[1];
  const float* W     = (const float*)d_in[2];
  float* out = (float*)d_out;

  const size_t need = ((size_t)2 * Bn * Sn * Hn + (size_t)Ln * Hn) * sizeof(bf16);
  if (ws_size >= need) {
    bf16* Xbf = (bf16*)d_ws;
    bf16* XT  = Xbf + (size_t)Bn * Sn * Hn;
    bf16* Wbf = XT  + (size_t)Bn * Sn * Hn;
    convert_x_kernel<<<dim3(Hn / 64, Sn / 64, Bn), 256, 0, stream>>>(X, Xbf, XT);
    convert_w_kernel<<<dim3((Ln * Hn) / 2048), 256, 0, stream>>>(W, Wbf);
    attn_main_kernel<<<dim3(Bn * (Ln / BL)), 256, 0, stream>>>(masks, Xbf, XT, Wbf, out);
  } else {
    attn_fallback_kernel<<<dim3(Bn * Ln / 4), 256, 0, stream>>>(X, masks, W, out);
  }
}

// Round 3
// 415.727 us; speedup vs baseline: 1.2298x; 1.1413x over previous
//
#include <hip/hip_runtime.h>
#include <hip/hip_bf16.h>

#define Bn 16
#define Sn 512
#define Hn 768
#define Ln 4096

typedef __attribute__((ext_vector_type(8))) short bf16x8;
typedef __attribute__((ext_vector_type(4))) float f32x4;

using bf16 = __hip_bfloat16;

constexpr int BL = 32;   // l-rows per block (halved from 64: occupancy 2->3 blocks/CU)

// ---- LDS layout (time-multiplexed, offsets in bytes) ----
// phase2:  Xs [512 rows][64 B]    @ 0       (32768)  row = s, 32 k bf16
//          Ws [ 32 rows][64 B]    @ 32768   (2048)   row = l-local
// phase5:  P  [32 rows][1024 B]   @ 0       (32768)  16B chunks XOR-swizzled: slot = chunk ^ (row&7)
//          XT [128 rows][128 B]   @ 32768   (16384)  row = h-local, chunks XOR-swizzled same way
// softmax: redm[2][32] f32        @ 49152   (256)
//          reds[2][32] f32        @ 49408   (256)
constexpr int SM_BYTES = 49664;  // 3 blocks/CU (148.9 KiB of 160)
constexpr int XS_OFF   = 0;
constexpr int WS_OFF   = 32768;
constexpr int P_OFF    = 0;
constexpr int XT_OFF   = 32768;
constexpr int REDM_OFF = 49152;
constexpr int REDS_OFF = 49408;

typedef const __attribute__((address_space(1))) unsigned int* gas_ptr;
typedef __attribute__((address_space(3))) unsigned int* las_ptr;

__device__ __forceinline__ void gld_lds16(const void* g, void* l) {
  // async 16B/lane global->LDS DMA; LDS dest = wave-uniform base + lane*16
  __builtin_amdgcn_global_load_lds((gas_ptr)g, (las_ptr)l, 16, 0, 0);
}

__device__ __forceinline__ unsigned short bfbits(float x) {
  __hip_bfloat16 h = __float2bfloat16(x);
  unsigned short u;
  __builtin_memcpy(&u, &h, 2);
  return u;
}

union Pack8 { bf16 h[8]; uint4 u; };

__device__ inline uint4 cvt8(float4 a, float4 b) {
  Pack8 p;
  p.h[0] = __float2bfloat16(a.x); p.h[1] = __float2bfloat16(a.y);
  p.h[2] = __float2bfloat16(a.z); p.h[3] = __float2bfloat16(a.w);
  p.h[4] = __float2bfloat16(b.x); p.h[5] = __float2bfloat16(b.y);
  p.h[6] = __float2bfloat16(b.z); p.h[7] = __float2bfloat16(b.w);
  return p.u;
}

// ---- pre-kernel: X fp32 -> bf16 row-major AND bf16 transposed [B][H][S] ----
__global__ __launch_bounds__(256) void convert_x_kernel(
    const float* __restrict__ X, bf16* __restrict__ Xbf, bf16* __restrict__ XT) {
  __shared__ bf16 t[64][72];
  const int tid = threadIdx.x;
  const int b  = blockIdx.z;
  const int s0 = blockIdx.y * 64;
  const int h0 = blockIdx.x * 64;
  const int r = tid >> 2;
  const int p = tid & 3;
  const float* src = X + ((size_t)b * Sn + s0 + r) * Hn + h0 + p * 16;
  float4 a0 = *(const float4*)(src + 0);
  float4 a1 = *(const float4*)(src + 4);
  float4 a2 = *(const float4*)(src + 8);
  float4 a3 = *(const float4*)(src + 12);
  uint4 u0 = cvt8(a0, a1);
  uint4 u1 = cvt8(a2, a3);
  bf16* xb = Xbf + ((size_t)b * Sn + s0 + r) * Hn + h0 + p * 16;
  *(uint4*)(xb)     = u0;
  *(uint4*)(xb + 8) = u1;
  *(uint4*)&t[r][p * 16]     = u0;
  *(uint4*)&t[r][p * 16 + 8] = u1;
  __syncthreads();
  Pack8 o0, o1;
#pragma unroll
  for (int i = 0; i < 8; ++i) {
    o0.h[i] = t[p * 16 + i][r];
    o1.h[i] = t[p * 16 + 8 + i][r];
  }
  bf16* xt = XT + ((size_t)b * Hn + h0 + r) * Sn + s0 + p * 16;
  *(uint4*)(xt)     = o0.u;
  *(uint4*)(xt + 8) = o1.u;
}

// ---- pre-kernel: W fp32 -> bf16 ----
__global__ __launch_bounds__(256) void convert_w_kernel(
    const float* __restrict__ W, bf16* __restrict__ Wbf) {
  const size_t i = ((size_t)blockIdx.x * 256 + threadIdx.x) * 8;
  float4 a0 = *(const float4*)(W + i);
  float4 a1 = *(const float4*)(W + i + 4);
  *(uint4*)(Wbf + i) = cvt8(a0, a1);
}

// ---- fused main kernel ----
// wave w: lg = w>>1 owns l rows lg*16..+15; sg = w&1 owns s half sg*256..+255 (phase2)
//         and nt-parity sg of each 128-h chunk (phase5)
__global__ __launch_bounds__(256, 3) void attn_main_kernel(
    const int* __restrict__ masks,
    const bf16* __restrict__ Xbf, const bf16* __restrict__ XTg,
    const bf16* __restrict__ Wbf, float* __restrict__ out) {
  __shared__ char sm[SM_BYTES];
  const int tid  = threadIdx.x;
  const int w    = tid >> 6;
  const int lane = tid & 63;
  const int col  = lane & 15;
  const int quad = lane >> 4;
  const int lg   = w >> 1;
  const int sg   = w & 1;
  // XCD-aware swizzle: 2048 blocks = 8 XCDs x 256 (bijective). Each XCD's
  // chunk spans 2 batches -> X/XT working set (~3.1 MB) stays L2-resident.
  const int vb = (blockIdx.x & 7) * 256 + (blockIdx.x >> 3);
  const int b  = vb >> 7;
  const int l0 = (vb & 127) * BL;

  // mask bias -> 16 regs (this lane's 16 s-columns within its half)
  float bias_r[16];
  {
    const int* mrow = masks + b * Sn + sg * 256 + col;
#pragma unroll
    for (int nt = 0; nt < 16; ++nt)
      bias_r[nt] = mrow[nt * 16] ? 0.0f : -1e30f;
  }

  const f32x4 zero = {0.f, 0.f, 0.f, 0.f};
  f32x4 acc[16];
#pragma unroll
  for (int nt = 0; nt < 16; ++nt) acc[nt] = zero;

  // ---- phase 2: scores[32l x 512s]; wave computes 16l x 256s ----
  for (int k0 = 0; k0 < Hn; k0 += 32) {
    __syncthreads();
    {
      // Xs: wave stages rows w*128..+127 (8 insts x 16 rows x 64B)
      const int r0 = w * 128;
      const bf16* g = Xbf + ((size_t)b * Sn + r0 + (lane >> 2)) * Hn + k0 + (lane & 3) * 8;
#pragma unroll
      for (int i = 0; i < 8; ++i) {
        gld_lds16(g, &sm[XS_OFF + (r0 + i * 16) * 64]);
        g += 16 * Hn;
      }
      // Ws: 32 rows; waves 0,1 stage 16 rows each
      if (w < 2) {
        const bf16* gw = Wbf + ((size_t)(l0 + w * 16 + (lane >> 2))) * Hn + k0 + (lane & 3) * 8;
        gld_lds16(gw, &sm[WS_OFF + (w * 16) * 64]);
      }
    }
    __syncthreads();
    bf16x8 aF = *(const bf16x8*)&sm[WS_OFF + (lg * 16 + col) * 64 + quad * 16];
#pragma unroll
    for (int nt = 0; nt < 16; ++nt) {
      bf16x8 bF = *(const bf16x8*)&sm[XS_OFF + (sg * 256 + nt * 16 + col) * 64 + quad * 16];
      acc[nt] = __builtin_amdgcn_mfma_f32_16x16x32_bf16(aF, bF, acc[nt], 0, 0, 0);
    }
  }

  // ---- phase 3: masked softmax, cross-wave (s split over sg) ----
  float* redm = (float*)&sm[REDM_OFF];
  float* reds = (float*)&sm[REDS_OFF];
  float mx[4];
#pragma unroll
  for (int r = 0; r < 4; ++r) mx[r] = -3e38f;
#pragma unroll
  for (int nt = 0; nt < 16; ++nt)
#pragma unroll
    for (int r = 0; r < 4; ++r) {
      acc[nt][r] += bias_r[nt];
      mx[r] = fmaxf(mx[r], acc[nt][r]);
    }
#pragma unroll
  for (int r = 0; r < 4; ++r) {
    mx[r] = fmaxf(mx[r], __shfl_xor(mx[r], 1, 64));
    mx[r] = fmaxf(mx[r], __shfl_xor(mx[r], 2, 64));
    mx[r] = fmaxf(mx[r], __shfl_xor(mx[r], 4, 64));
    mx[r] = fmaxf(mx[r], __shfl_xor(mx[r], 8, 64));
  }
  if (col == 0) {
#pragma unroll
    for (int r = 0; r < 4; ++r)
      redm[sg * 32 + lg * 16 + quad * 4 + r] = mx[r];
  }
  __syncthreads();
  float gmax[4], sum[4];
#pragma unroll
  for (int r = 0; r < 4; ++r) {
    const int row = lg * 16 + quad * 4 + r;
    gmax[r] = fmaxf(redm[row], redm[32 + row]);
    sum[r] = 0.f;
  }
#pragma unroll
  for (int nt = 0; nt < 16; ++nt)
#pragma unroll
    for (int r = 0; r < 4; ++r) {
      const float e = __expf(acc[nt][r] - gmax[r]);
      acc[nt][r] = e;
      sum[r] += e;
    }
#pragma unroll
  for (int r = 0; r < 4; ++r) {
    sum[r] += __shfl_xor(sum[r], 1, 64);
    sum[r] += __shfl_xor(sum[r], 2, 64);
    sum[r] += __shfl_xor(sum[r], 4, 64);
    sum[r] += __shfl_xor(sum[r], 8, 64);
  }
  if (col == 0) {
#pragma unroll
    for (int r = 0; r < 4; ++r)
      reds[sg * 32 + lg * 16 + quad * 4 + r] = sum[r];
  }
  __syncthreads();
  float rs[4];
#pragma unroll
  for (int r = 0; r < 4; ++r) {
    const int row = lg * 16 + quad * 4 + r;
    rs[r] = 1.0f / (reds[row] + reds[32 + row]);
  }

  // ---- phase 4: P (unnormalized exp) -> LDS bf16, b32 packed via shfl pairing ----
  // P row = 1024 B (512 bf16). 16B chunk c of row stored at slot c ^ (row&7).
  const int pi = col & 1;  // parity
#pragma unroll
  for (int t = 0; t < 8; ++t)
#pragma unroll
    for (int r = 0; r < 4; ++r) {
      const float own0 = acc[2 * t][r];
      const float own1 = acc[2 * t + 1][r];
      const float p0 = __shfl_xor(own0, 1, 64);  // partner's nt=2t value
      const float p1 = __shfl_xor(own1, 1, 64);  // partner's nt=2t+1 value
      const float lo = pi ? p1 : own0;
      const float hi = pi ? own1 : p0;
      const unsigned pk = (unsigned)bfbits(lo) | ((unsigned)bfbits(hi) << 16);
      const int nt_w = 2 * t + pi;
      const int row = lg * 16 + quad * 4 + r;
      const int sp = sg * 256 + nt_w * 16 + (col & ~1);
      const int slot = (sp >> 3) ^ (row & 7);
      *(unsigned*)&sm[P_OFF + row * 1024 + slot * 16 + (sp & 7) * 2] = pk;
    }

  // ---- phase 5: O[32l x 768h] = P[32,512] x X[512,768] ----
  for (int n0 = 0; n0 < Hn / 128; ++n0) {
    f32x4 oacc[4];
#pragma unroll
    for (int nt = 0; nt < 4; ++nt) oacc[nt] = zero;
    for (int s0 = 0; s0 < Sn; s0 += 64) {
      __syncthreads();
      {
        // XT tile: 128 h-rows x 64 s; wave stages rows w*32..+31 (4 insts x 8 rows x 128B)
        // chunk swizzle at the SOURCE: lane (rr,cc) fetches s-chunk cc^rr so that
        // row rr's chunk c lands at LDS slot c^rr.
        const int r0 = w * 32;
        const int rr = lane >> 3;
        const int cc = lane & 7;
        const bf16* g = XTg + ((size_t)b * Hn + n0 * 128 + r0 + rr) * Sn + s0 + (cc ^ rr) * 8;
#pragma unroll
        for (int i = 0; i < 4; ++i) {
          gld_lds16(g, &sm[XT_OFF + (r0 + i * 8) * 128]);
          g += 8 * Sn;
        }
      }
      __syncthreads();
#pragma unroll
      for (int ks = 0; ks < 2; ++ks) {
        const int chunk = (s0 + ks * 32 + quad * 8) >> 3;
        const int row = lg * 16 + col;
        const int slot = chunk ^ (row & 7);
        bf16x8 pa = *(const bf16x8*)&sm[P_OFF + row * 1024 + slot * 16];
#pragma unroll
        for (int nt = 0; nt < 4; ++nt) {
          const int hl = (nt * 2 + sg) * 16 + col;
          const int xslot = (ks * 4 + quad) ^ (hl & 7);
          bf16x8 xb = *(const bf16x8*)&sm[XT_OFF + hl * 128 + xslot * 16];
          oacc[nt] = __builtin_amdgcn_mfma_f32_16x16x32_bf16(pa, xb, oacc[nt], 0, 0, 0);
        }
      }
    }
#pragma unroll
    for (int nt = 0; nt < 4; ++nt) {
      const int h = n0 * 128 + (nt * 2 + sg) * 16 + col;
      const int lbase = l0 + lg * 16 + quad * 4;
#pragma unroll
      for (int r = 0; r < 4; ++r)
        out[((size_t)b * Ln + lbase + r) * Hn + h] = oacc[nt][r] * rs[r];
    }
  }
}

// ---- fallback (ws too small): fp32 wave-per-(b,l), slow but correct ----
__global__ __launch_bounds__(256) void attn_fallback_kernel(
    const float* __restrict__ X, const int* __restrict__ masks,
    const float* __restrict__ W, float* __restrict__ out) {
  __shared__ float sc[4][Sn];
  const int wv = threadIdx.x >> 6, lane = threadIdx.x & 63;
  const int gw = blockIdx.x * 4 + wv;
  const int b = gw / Ln, l = gw % Ln;
  float wreg[12];
#pragma unroll
  for (int j = 0; j < 12; ++j) wreg[j] = W[(size_t)l * Hn + j * 64 + lane];
  for (int s = 0; s < Sn; ++s) {
    const float* xr = X + ((size_t)b * Sn + s) * Hn;
    float p = 0.f;
#pragma unroll
    for (int j = 0; j < 12; ++j) p += xr[j * 64 + lane] * wreg[j];
#pragma unroll
    for (int off = 32; off > 0; off >>= 1) p += __shfl_xor(p, off, 64);
    if (lane == 0) sc[wv][s] = p;
  }
  __syncthreads();
  float m = -3e38f;
#pragma unroll
  for (int i = 0; i < 8; ++i) {
    const int s = lane * 8 + i;
    const float v = sc[wv][s] + (masks[b * Sn + s] ? 0.f : -1e30f);
    sc[wv][s] = v;
    m = fmaxf(m, v);
  }
#pragma unroll
  for (int off = 32; off > 0; off >>= 1) m = fmaxf(m, __shfl_xor(m, off, 64));
  __syncthreads();
  float sum = 0.f;
#pragma unroll
  for (int i = 0; i < 8; ++i) {
    const int s = lane * 8 + i;
    const float e = __expf(sc[wv][s] - m);
    sc[wv][s] = e;
    sum += e;
  }
#pragma unroll
  for (int off = 32; off > 0; off >>= 1) sum += __shfl_xor(sum, off, 64);
  const float rs = 1.0f / sum;
  __syncthreads();
  float o[12];
#pragma unroll
  for (int j = 0; j < 12; ++j) o[j] = 0.f;
  for (int s = 0; s < Sn; ++s) {
    const float p = sc[wv][s];
    const float* xr = X + ((size_t)b * Sn + s) * Hn;
#pragma unroll
    for (int j = 0; j < 12; ++j) o[j] += p * xr[j * 64 + lane];
  }
#pragma unroll
  for (int j = 0; j < 12; ++j)
    out[((size_t)b * Ln + l) * Hn + j * 64 + lane] = o[j] * rs;
}

extern "C" void kernel_launch(void* const* d_in, const int* in_sizes, int n_in,
                              void* d_out, int out_size, void* d_ws, size_t ws_size,
                              hipStream_t stream) {
  const float* X     = (const float*)d_in[0];
  const int*   masks = (const int*)d_in[1];
  const float* W     = (const float*)d_in[2];
  float* out = (float*)d_out;

  const size_t need = ((size_t)2 * Bn * Sn * Hn + (size_t)Ln * Hn) * sizeof(bf16);
  if (ws_size >= need) {
    bf16* Xbf = (bf16*)d_ws;
    bf16* XT  = Xbf + (size_t)Bn * Sn * Hn;
    bf16* Wbf = XT  + (size_t)Bn * Sn * Hn;
    convert_x_kernel<<<dim3(Hn / 64, Sn / 64, Bn), 256, 0, stream>>>(X, Xbf, XT);
    convert_w_kernel<<<dim3((Ln * Hn) / 2048), 256, 0, stream>>>(W, Wbf);
    attn_main_kernel<<<dim3(Bn * (Ln / BL)), 256, 0, stream>>>(masks, Xbf, XT, Wbf, out);
  } else {
    attn_fallback_kernel<<<dim3(Bn * Ln / 4), 256, 0, stream>>>(X, masks, W, out);
  }
}

// Round 4
// 372.364 us; speedup vs baseline: 1.3730x; 1.1165x over previous
//
#include <hip/hip_runtime.h>
#include <hip/hip_bf16.h>

#define Bn 16
#define Sn 512
#define Hn 768
#define Ln 4096

typedef __attribute__((ext_vector_type(8))) short bf16x8;
typedef __attribute__((ext_vector_type(4))) float f32x4;

using bf16 = __hip_bfloat16;

constexpr int BL = 64;   // l-rows per block

// ---- LDS layout (time-multiplexed, offsets in bytes) ----
// phase2:  DOUBLE-BUFFERED {Xs [512][64B] @ +0, Ws [64][64B] @ +32768} = 36864/buf
//          buf0 @ 0, buf1 @ 36864 (compile-time offsets; loop 2x-unrolled)
// softmax: redm[2][64] f32        @ 73728   (512)
//          reds[2][64] f32        @ 74240   (512)
// phase5:  P  [64 rows][1024 B]   @ 0       (65536)  16B chunks XOR-swizzled: slot = chunk ^ (row&7)
//          XT [128 rows][128 B]   @ 65536   (16384)  row = h-local, chunks XOR-swizzled same way
constexpr int SM_BYTES  = 81920;  // 2 blocks/CU
constexpr int PH2_BUF   = 36864;
constexpr int WS_OFF_IN = 32768;  // within a phase-2 buffer
constexpr int P_OFF     = 0;
constexpr int XT_OFF    = 65536;
constexpr int REDM_OFF  = 73728;
constexpr int REDS_OFF  = 74240;

typedef const __attribute__((address_space(1))) unsigned int* gas_ptr;
typedef __attribute__((address_space(3))) unsigned int* las_ptr;

__device__ __forceinline__ void gld_lds16(const void* g, void* l) {
  // async 16B/lane global->LDS DMA; LDS dest = wave-uniform base + lane*16
  __builtin_amdgcn_global_load_lds((gas_ptr)g, (las_ptr)l, 16, 0, 0);
}

__device__ __forceinline__ unsigned short bfbits(float x) {
  __hip_bfloat16 h = __float2bfloat16(x);
  unsigned short u;
  __builtin_memcpy(&u, &h, 2);
  return u;
}

union Pack8 { bf16 h[8]; uint4 u; };

__device__ inline uint4 cvt8(float4 a, float4 b) {
  Pack8 p;
  p.h[0] = __float2bfloat16(a.x); p.h[1] = __float2bfloat16(a.y);
  p.h[2] = __float2bfloat16(a.z); p.h[3] = __float2bfloat16(a.w);
  p.h[4] = __float2bfloat16(b.x); p.h[5] = __float2bfloat16(b.y);
  p.h[6] = __float2bfloat16(b.z); p.h[7] = __float2bfloat16(b.w);
  return p.u;
}

// ---- pre-kernel: X fp32 -> bf16 row-major AND bf16 transposed [B][H][S] ----
__global__ __launch_bounds__(256) void convert_x_kernel(
    const float* __restrict__ X, bf16* __restrict__ Xbf, bf16* __restrict__ XT) {
  __shared__ bf16 t[64][72];
  const int tid = threadIdx.x;
  const int b  = blockIdx.z;
  const int s0 = blockIdx.y * 64;
  const int h0 = blockIdx.x * 64;
  const int r = tid >> 2;
  const int p = tid & 3;
  const float* src = X + ((size_t)b * Sn + s0 + r) * Hn + h0 + p * 16;
  float4 a0 = *(const float4*)(src + 0);
  float4 a1 = *(const float4*)(src + 4);
  float4 a2 = *(const float4*)(src + 8);
  float4 a3 = *(const float4*)(src + 12);
  uint4 u0 = cvt8(a0, a1);
  uint4 u1 = cvt8(a2, a3);
  bf16* xb = Xbf + ((size_t)b * Sn + s0 + r) * Hn + h0 + p * 16;
  *(uint4*)(xb)     = u0;
  *(uint4*)(xb + 8) = u1;
  *(uint4*)&t[r][p * 16]     = u0;
  *(uint4*)&t[r][p * 16 + 8] = u1;
  __syncthreads();
  Pack8 o0, o1;
#pragma unroll
  for (int i = 0; i < 8; ++i) {
    o0.h[i] = t[p * 16 + i][r];
    o1.h[i] = t[p * 16 + 8 + i][r];
  }
  bf16* xt = XT + ((size_t)b * Hn + h0 + r) * Sn + s0 + p * 16;
  *(uint4*)(xt)     = o0.u;
  *(uint4*)(xt + 8) = o1.u;
}

// ---- pre-kernel: W fp32 -> bf16 ----
__global__ __launch_bounds__(256) void convert_w_kernel(
    const float* __restrict__ W, bf16* __restrict__ Wbf) {
  const size_t i = ((size_t)blockIdx.x * 256 + threadIdx.x) * 8;
  float4 a0 = *(const float4*)(W + i);
  float4 a1 = *(const float4*)(W + i + 4);
  *(uint4*)(Wbf + i) = cvt8(a0, a1);
}

// ---- fused main kernel ----
// wave w: lg = w>>1 owns l rows lg*32..+31; sg = w&1 owns s half sg*256..+255 (phase2)
//         and nt-parity sg of each 128-h chunk (phase5)
__global__ __launch_bounds__(256, 2) void attn_main_kernel(
    const int* __restrict__ masks,
    const bf16* __restrict__ Xbf, const bf16* __restrict__ XTg,
    const bf16* __restrict__ Wbf, float* __restrict__ out) {
  __shared__ char sm[SM_BYTES];
  const int tid  = threadIdx.x;
  const int w    = tid >> 6;
  const int lane = tid & 63;
  const int col  = lane & 15;
  const int quad = lane >> 4;
  const int lg   = w >> 1;
  const int sg   = w & 1;
  // XCD-aware swizzle: 1024 blocks = 8 XCDs x 128 (bijective). Each XCD's
  // resident blocks share 2 batches -> X/XT working set stays L2-resident.
  // (validated: FETCH 104.7 -> 61.6 MB in rounds 2/3)
  const int vb = (blockIdx.x & 7) * 128 + (blockIdx.x >> 3);
  const int b  = vb >> 6;
  const int l0 = (vb & 63) * BL;

  // mask bias -> 16 regs (this lane's 16 s-columns within its half)
  float bias_r[16];
  {
    const int* mrow = masks + b * Sn + sg * 256 + col;
#pragma unroll
    for (int nt = 0; nt < 16; ++nt)
      bias_r[nt] = mrow[nt * 16] ? 0.0f : -1e30f;
  }

  const f32x4 zero = {0.f, 0.f, 0.f, 0.f};
  f32x4 acc[2][16];
#pragma unroll
  for (int a = 0; a < 2; ++a)
#pragma unroll
    for (int nt = 0; nt < 16; ++nt) acc[a][nt] = zero;

  // ---- phase 2: scores[64l x 512s]; wave computes 32l x 256s ----
  // Static-parity double-buffer: issue stage(k+1) BEFORE compute(k); drain with
  // asm vmcnt(0) + raw s_barrier (loads were issued ~32 MFMA + 18 ds_read earlier,
  // so the wait is short -- unlike round 0's issue-then-immediately-drain).
  const int rr2 = lane >> 2;        // staging row within 16-row group
  const int cc2 = (lane & 3) * 8;   // staging k-offset (elements)

#define STAGE2(BUFOFF, K0)                                                         \
  {                                                                                \
    const bf16* gx = Xbf + ((size_t)b * Sn + w * 128 + rr2) * Hn + (K0) + cc2;     \
    char* dx = sm + (BUFOFF) + (w * 128) * 64;                                     \
    _Pragma("unroll")                                                              \
    for (int i = 0; i < 8; ++i) {                                                  \
      gld_lds16(gx, dx);                                                           \
      gx += 16 * Hn;                                                               \
      dx += 16 * 64;                                                               \
    }                                                                              \
    const bf16* gw = Wbf + ((size_t)(l0 + w * 16 + rr2)) * Hn + (K0) + cc2;        \
    gld_lds16(gw, sm + (BUFOFF) + WS_OFF_IN + (w * 16) * 64);                      \
  }

#define PH2_COMPUTE(BUFOFF)                                                        \
  {                                                                                \
    const char* xs = sm + (BUFOFF);                                                \
    const char* ws = sm + (BUFOFF) + WS_OFF_IN;                                    \
    bf16x8 a0 = *(const bf16x8*)&ws[(lg * 32 + col) * 64 + quad * 16];             \
    bf16x8 a1 = *(const bf16x8*)&ws[(lg * 32 + 16 + col) * 64 + quad * 16];        \
    _Pragma("unroll")                                                              \
    for (int nt = 0; nt < 16; ++nt) {                                              \
      bf16x8 bf_ = *(const bf16x8*)&xs[(sg * 256 + nt * 16 + col) * 64 + quad * 16]; \
      acc[0][nt] = __builtin_amdgcn_mfma_f32_16x16x32_bf16(a0, bf_, acc[0][nt], 0, 0, 0); \
      acc[1][nt] = __builtin_amdgcn_mfma_f32_16x16x32_bf16(a1, bf_, acc[1][nt], 0, 0, 0); \
    }                                                                              \
  }

  STAGE2(0, 0);
  asm volatile("s_waitcnt vmcnt(0)" ::: "memory");
  __builtin_amdgcn_s_barrier();
  for (int k0 = 0; k0 < Hn; k0 += 64) {
    // half A: compute buf0 (holds k0), prefetch k0+32 into buf1
    STAGE2(PH2_BUF, k0 + 32);        // k0+32 <= 736 always valid
    PH2_COMPUTE(0);
    asm volatile("s_waitcnt vmcnt(0)" ::: "memory");  // buf1 staged (issued pre-compute)
    __builtin_amdgcn_s_barrier();                     // buf1 published; buf0 free
    // half B: compute buf1 (holds k0+32), prefetch k0+64 into buf0
    if (k0 + 64 < Hn) STAGE2(0, k0 + 64);
    PH2_COMPUTE(PH2_BUF);
    asm volatile("s_waitcnt vmcnt(0)" ::: "memory");
    __builtin_amdgcn_s_barrier();
  }
#undef STAGE2
#undef PH2_COMPUTE

  // ---- phase 3: masked softmax, cross-wave (s split over sg) ----
  float* redm = (float*)&sm[REDM_OFF];
  float* reds = (float*)&sm[REDS_OFF];
  float mx[2][4];
#pragma unroll
  for (int a = 0; a < 2; ++a)
#pragma unroll
    for (int r = 0; r < 4; ++r) mx[a][r] = -3e38f;
#pragma unroll
  for (int a = 0; a < 2; ++a)
#pragma unroll
    for (int nt = 0; nt < 16; ++nt)
#pragma unroll
      for (int r = 0; r < 4; ++r) {
        acc[a][nt][r] += bias_r[nt];
        mx[a][r] = fmaxf(mx[a][r], acc[a][nt][r]);
      }
#pragma unroll
  for (int a = 0; a < 2; ++a)
#pragma unroll
    for (int r = 0; r < 4; ++r) {
      mx[a][r] = fmaxf(mx[a][r], __shfl_xor(mx[a][r], 1, 64));
      mx[a][r] = fmaxf(mx[a][r], __shfl_xor(mx[a][r], 2, 64));
      mx[a][r] = fmaxf(mx[a][r], __shfl_xor(mx[a][r], 4, 64));
      mx[a][r] = fmaxf(mx[a][r], __shfl_xor(mx[a][r], 8, 64));
    }
  if (col == 0) {
#pragma unroll
    for (int a = 0; a < 2; ++a)
#pragma unroll
      for (int r = 0; r < 4; ++r)
        redm[sg * 64 + lg * 32 + a * 16 + quad * 4 + r] = mx[a][r];
  }
  __syncthreads();
  float gmax[2][4], sum[2][4];
#pragma unroll
  for (int a = 0; a < 2; ++a)
#pragma unroll
    for (int r = 0; r < 4; ++r) {
      const int row = lg * 32 + a * 16 + quad * 4 + r;
      gmax[a][r] = fmaxf(redm[row], redm[64 + row]);
      sum[a][r] = 0.f;
    }
#pragma unroll
  for (int a = 0; a < 2; ++a)
#pragma unroll
    for (int nt = 0; nt < 16; ++nt)
#pragma unroll
      for (int r = 0; r < 4; ++r) {
        const float e = __expf(acc[a][nt][r] - gmax[a][r]);
        acc[a][nt][r] = e;
        sum[a][r] += e;
      }
#pragma unroll
  for (int a = 0; a < 2; ++a)
#pragma unroll
    for (int r = 0; r < 4; ++r) {
      sum[a][r] += __shfl_xor(sum[a][r], 1, 64);
      sum[a][r] += __shfl_xor(sum[a][r], 2, 64);
      sum[a][r] += __shfl_xor(sum[a][r], 4, 64);
      sum[a][r] += __shfl_xor(sum[a][r], 8, 64);
    }
  if (col == 0) {
#pragma unroll
    for (int a = 0; a < 2; ++a)
#pragma unroll
      for (int r = 0; r < 4; ++r)
        reds[sg * 64 + lg * 32 + a * 16 + quad * 4 + r] = sum[a][r];
  }
  __syncthreads();
  float rs[2][4];
#pragma unroll
  for (int a = 0; a < 2; ++a)
#pragma unroll
    for (int r = 0; r < 4; ++r) {
      const int row = lg * 32 + a * 16 + quad * 4 + r;
      rs[a][r] = 1.0f / (reds[row] + reds[64 + row]);
    }

  // ---- phase 4: P (unnormalized exp) -> LDS bf16, b32 packed via shfl pairing ----
  // P row = 1024 B (512 bf16). 16B chunk c of row stored at slot c ^ (row&7).
  const int pi = col & 1;  // parity
#pragma unroll
  for (int a = 0; a < 2; ++a)
#pragma unroll
    for (int t = 0; t < 8; ++t)
#pragma unroll
      for (int r = 0; r < 4; ++r) {
        const float own0 = acc[a][2 * t][r];
        const float own1 = acc[a][2 * t + 1][r];
        const float p0 = __shfl_xor(own0, 1, 64);  // partner's nt=2t value
        const float p1 = __shfl_xor(own1, 1, 64);  // partner's nt=2t+1 value
        const float lo = pi ? p1 : own0;
        const float hi = pi ? own1 : p0;
        const unsigned pk = (unsigned)bfbits(lo) | ((unsigned)bfbits(hi) << 16);
        const int nt_w = 2 * t + pi;
        const int row = lg * 32 + a * 16 + quad * 4 + r;
        const int sp = sg * 256 + nt_w * 16 + (col & ~1);
        const int slot = (sp >> 3) ^ (row & 7);
        *(unsigned*)&sm[P_OFF + row * 1024 + slot * 16 + (sp & 7) * 2] = pk;
      }

  // ---- phase 5: O[64l x 768h] = P[64,512] x X[512,768] ----
  for (int n0 = 0; n0 < Hn / 128; ++n0) {
    f32x4 oacc[2][4];
#pragma unroll
    for (int a = 0; a < 2; ++a)
#pragma unroll
      for (int nt = 0; nt < 4; ++nt) oacc[a][nt] = zero;
    for (int s0 = 0; s0 < Sn; s0 += 64) {
      __syncthreads();
      {
        // XT tile: 128 h-rows x 64 s; wave stages rows w*32..+31 (4 insts x 8 rows x 128B)
        // chunk swizzle at the SOURCE: lane (rr,cc) fetches s-chunk cc^rr so that
        // row rr's chunk c lands at LDS slot c^rr.
        const int r0 = w * 32;
        const int rr = lane >> 3;
        const int cc = lane & 7;
        const bf16* g = XTg + ((size_t)b * Hn + n0 * 128 + r0 + rr) * Sn + s0 + (cc ^ rr) * 8;
#pragma unroll
        for (int i = 0; i < 4; ++i) {
          gld_lds16(g, &sm[XT_OFF + (r0 + i * 8) * 128]);
          g += 8 * Sn;
        }
      }
      __syncthreads();
#pragma unroll
      for (int ks = 0; ks < 2; ++ks) {
        const int chunk = (s0 + ks * 32 + quad * 8) >> 3;
        bf16x8 pa[2];
#pragma unroll
        for (int a = 0; a < 2; ++a) {
          const int row = lg * 32 + a * 16 + col;
          const int slot = chunk ^ (row & 7);
          pa[a] = *(const bf16x8*)&sm[P_OFF + row * 1024 + slot * 16];
        }
#pragma unroll
        for (int nt = 0; nt < 4; ++nt) {
          const int hl = (nt * 2 + sg) * 16 + col;
          const int xslot = (ks * 4 + quad) ^ (hl & 7);
          bf16x8 xb = *(const bf16x8*)&sm[XT_OFF + hl * 128 + xslot * 16];
          oacc[0][nt] = __builtin_amdgcn_mfma_f32_16x16x32_bf16(pa[0], xb, oacc[0][nt], 0, 0, 0);
          oacc[1][nt] = __builtin_amdgcn_mfma_f32_16x16x32_bf16(pa[1], xb, oacc[1][nt], 0, 0, 0);
        }
      }
    }
#pragma unroll
    for (int a = 0; a < 2; ++a)
#pragma unroll
      for (int nt = 0; nt < 4; ++nt) {
        const int h = n0 * 128 + (nt * 2 + sg) * 16 + col;
        const int lbase = l0 + lg * 32 + a * 16 + quad * 4;
#pragma unroll
        for (int r = 0; r < 4; ++r)
          out[((size_t)b * Ln + lbase + r) * Hn + h] = oacc[a][nt][r] * rs[a][r];
      }
  }
}

// ---- fallback (ws too small): fp32 wave-per-(b,l), slow but correct ----
__global__ __launch_bounds__(256) void attn_fallback_kernel(
    const float* __restrict__ X, const int* __restrict__ masks,
    const float* __restrict__ W, float* __restrict__ out) {
  __shared__ float sc[4][Sn];
  const int wv = threadIdx.x >> 6, lane = threadIdx.x & 63;
  const int gw = blockIdx.x * 4 + wv;
  const int b = gw / Ln, l = gw % Ln;
  float wreg[12];
#pragma unroll
  for (int j = 0; j < 12; ++j) wreg[j] = W[(size_t)l * Hn + j * 64 + lane];
  for (int s = 0; s < Sn; ++s) {
    const float* xr = X + ((size_t)b * Sn + s) * Hn;
    float p = 0.f;
#pragma unroll
    for (int j = 0; j < 12; ++j) p += xr[j * 64 + lane] * wreg[j];
#pragma unroll
    for (int off = 32; off > 0; off >>= 1) p += __shfl_xor(p, off, 64);
    if (lane == 0) sc[wv][s] = p;
  }
  __syncthreads();
  float m = -3e38f;
#pragma unroll
  for (int i = 0; i < 8; ++i) {
    const int s = lane * 8 + i;
    const float v = sc[wv][s] + (masks[b * Sn + s] ? 0.f : -1e30f);
    sc[wv][s] = v;
    m = fmaxf(m, v);
  }
#pragma unroll
  for (int off = 32; off > 0; off >>= 1) m = fmaxf(m, __shfl_xor(m, off, 64));
  __syncthreads();
  float sum = 0.f;
#pragma unroll
  for (int i = 0; i < 8; ++i) {
    const int s = lane * 8 + i;
    const float e = __expf(sc[wv][s] - m);
    sc[wv][s] = e;
    sum += e;
  }
#pragma unroll
  for (int off = 32; off > 0; off >>= 1) sum += __shfl_xor(sum, off, 64);
  const float rs = 1.0f / sum;
  __syncthreads();
  float o[12];
#pragma unroll
  for (int j = 0; j < 12; ++j) o[j] = 0.f;
  for (int s = 0; s < Sn; ++s) {
    const float p = sc[wv][s];
    const float* xr = X + ((size_t)b * Sn + s) * Hn;
#pragma unroll
    for (int j = 0; j < 12; ++j) o[j] += p * xr[j * 64 + lane];
  }
#pragma unroll
  for (int j = 0; j < 12; ++j)
    out[((size_t)b * Ln + l) * Hn + j * 64 + lane] = o[j] * rs;
}

extern "C" void kernel_launch(void* const* d_in, const int* in_sizes, int n_in,
                              void* d_out, int out_size, void* d_ws, size_t ws_size,
                              hipStream_t stream) {
  const float* X     = (const float*)d_in[0];
  const int*   masks = (const int*)d_in[1];
  const float* W     = (const float*)d_in[2];
  float* out = (float*)d_out;

  const size_t need = ((size_t)2 * Bn * Sn * Hn + (size_t)Ln * Hn) * sizeof(bf16);
  if (ws_size >= need) {
    bf16* Xbf = (bf16*)d_ws;
    bf16* XT  = Xbf + (size_t)Bn * Sn * Hn;
    bf16* Wbf = XT  + (size_t)Bn * Sn * Hn;
    convert_x_kernel<<<dim3(Hn / 64, Sn / 64, Bn), 256, 0, stream>>>(X, Xbf, XT);
    convert_w_kernel<<<dim3((Ln * Hn) / 2048), 256, 0, stream>>>(W, Wbf);
    attn_main_kernel<<<dim3(Bn * (Ln / BL)), 256, 0, stream>>>(masks, Xbf, XT, Wbf, out);
  } else {
    attn_fallback_kernel<<<dim3(Bn * Ln / 4), 256, 0, stream>>>(X, masks, W, out);
  }
}

// Round 6
// 359.259 us; speedup vs baseline: 1.4231x; 1.0365x over previous
//
#include <hip/hip_runtime.h>
#include <hip/hip_bf16.h>

#define Bn 16
#define Sn 512
#define Hn 768
#define Ln 4096

typedef __attribute__((ext_vector_type(8))) short bf16x8;
typedef __attribute__((ext_vector_type(4))) float f32x4;

using bf16 = __hip_bfloat16;

constexpr int BL = 64;   // l-rows per block

// ---- LDS layout (time-multiplexed, offsets in bytes) ----
// phase2:  DOUBLE-BUFFERED {Xs [512][64B] @ +0, Ws [64][64B] @ +32768} = 36864/buf
//          buf0 @ 0, buf1 @ 36864 (ends 73728)
// softmax: redm[4][64] f32 @ 73728 (1024), reds[4][64] f32 @ 74752 (1024)
// phase4:  P [64 rows][1024 B] @ 0 (65536), chunks swizzled slot = chunk ^ (row&7)
// phase5:  P hoisted to regs, then XT dbuf in freed space: buf0 @ 0, buf1 @ 16384
constexpr int SM_BYTES  = 75776;  // 2 blocks/CU (151.5 KiB of 160)
constexpr int PH2_BUF   = 36864;
constexpr int WS_OFF_IN = 32768;  // within a phase-2 buffer
constexpr int P_OFF     = 0;
constexpr int REDM_OFF  = 73728;
constexpr int REDS_OFF  = 74752;

typedef const __attribute__((address_space(1))) unsigned int* gas_ptr;
typedef __attribute__((address_space(3))) unsigned int* las_ptr;

__device__ __forceinline__ void gld_lds16(const void* g, void* l) {
  // async 16B/lane global->LDS DMA; LDS dest = wave-uniform base + lane*16
  __builtin_amdgcn_global_load_lds((gas_ptr)g, (las_ptr)l, 16, 0, 0);
}

__device__ __forceinline__ unsigned short bfbits(float x) {
  __hip_bfloat16 h = __float2bfloat16(x);
  unsigned short u;
  __builtin_memcpy(&u, &h, 2);
  return u;
}

union Pack8 { bf16 h[8]; uint4 u; };

__device__ inline uint4 cvt8(float4 a, float4 b) {
  Pack8 p;
  p.h[0] = __float2bfloat16(a.x); p.h[1] = __float2bfloat16(a.y);
  p.h[2] = __float2bfloat16(a.z); p.h[3] = __float2bfloat16(a.w);
  p.h[4] = __float2bfloat16(b.x); p.h[5] = __float2bfloat16(b.y);
  p.h[6] = __float2bfloat16(b.z); p.h[7] = __float2bfloat16(b.w);
  return p.u;
}

// ---- pre-kernel: X fp32 -> bf16 row-major AND bf16 transposed [B][H][S] ----
__global__ __launch_bounds__(256) void convert_x_kernel(
    const float* __restrict__ X, bf16* __restrict__ Xbf, bf16* __restrict__ XT) {
  __shared__ bf16 t[64][72];
  const int tid = threadIdx.x;
  const int b  = blockIdx.z;
  const int s0 = blockIdx.y * 64;
  const int h0 = blockIdx.x * 64;
  const int r = tid >> 2;
  const int p = tid & 3;
  const float* src = X + ((size_t)b * Sn + s0 + r) * Hn + h0 + p * 16;
  float4 a0 = *(const float4*)(src + 0);
  float4 a1 = *(const float4*)(src + 4);
  float4 a2 = *(const float4*)(src + 8);
  float4 a3 = *(const float4*)(src + 12);
  uint4 u0 = cvt8(a0, a1);
  uint4 u1 = cvt8(a2, a3);
  bf16* xb = Xbf + ((size_t)b * Sn + s0 + r) * Hn + h0 + p * 16;
  *(uint4*)(xb)     = u0;
  *(uint4*)(xb + 8) = u1;
  *(uint4*)&t[r][p * 16]     = u0;
  *(uint4*)&t[r][p * 16 + 8] = u1;
  __syncthreads();
  Pack8 o0, o1;
#pragma unroll
  for (int i = 0; i < 8; ++i) {
    o0.h[i] = t[p * 16 + i][r];
    o1.h[i] = t[p * 16 + 8 + i][r];
  }
  bf16* xt = XT + ((size_t)b * Hn + h0 + r) * Sn + s0 + p * 16;
  *(uint4*)(xt)     = o0.u;
  *(uint4*)(xt + 8) = o1.u;
}

// ---- pre-kernel: W fp32 -> bf16 ----
__global__ __launch_bounds__(256) void convert_w_kernel(
    const float* __restrict__ W, bf16* __restrict__ Wbf) {
  const size_t i = ((size_t)blockIdx.x * 256 + threadIdx.x) * 8;
  float4 a0 = *(const float4*)(W + i);
  float4 a1 = *(const float4*)(W + i + 4);
  *(uint4*)(Wbf + i) = cvt8(a0, a1);
}

// ---- fused main kernel (4 waves / 256 threads) ----
// phase2: wave w owns s-slice [w*128, w*128+128); tile M=64 x N=128 (12 reads/k-step)
// phase5: lg = w>>1 owns l rows lg*32..+31; sg = w&1 owns nt-parity of 128-h chunk
__global__ __launch_bounds__(256, 2) void attn_main_kernel(
    const int* __restrict__ masks,
    const bf16* __restrict__ Xbf, const bf16* __restrict__ XTg,
    const bf16* __restrict__ Wbf, float* __restrict__ out) {
  __shared__ char sm[SM_BYTES];
  const int tid  = threadIdx.x;
  const int w    = tid >> 6;
  const int lane = tid & 63;
  const int col  = lane & 15;
  const int quad = lane >> 4;
  const int lg   = w >> 1;
  const int sg   = w & 1;
  // XCD-aware swizzle: 1024 blocks = 8 XCDs x 128 (bijective).
  // Validated: FETCH 104.7 -> 63 MB.
  const int vb = (blockIdx.x & 7) * 128 + (blockIdx.x >> 3);
  const int b  = vb >> 6;
  const int l0 = (vb & 63) * BL;

  // mask bias -> 8 regs (this lane's 8 s-columns within the wave's 128-slice)
  float bias_r[8];
  {
    const int* mrow = masks + b * Sn + w * 128 + col;
#pragma unroll
    for (int nt = 0; nt < 8; ++nt)
      bias_r[nt] = mrow[nt * 16] ? 0.0f : -1e30f;
  }

  const f32x4 zero = {0.f, 0.f, 0.f, 0.f};
  f32x4 acc[4][8];
#pragma unroll
  for (int am = 0; am < 4; ++am)
#pragma unroll
    for (int nt = 0; nt < 8; ++nt) acc[am][nt] = zero;

  // ---- phase 2: scores[64l x 512s]; wave tile M=64 x N=128, static dbuf ----
  const int rr2 = lane >> 2;        // staging row within 16-row group
  const int cc2 = (lane & 3) * 8;   // staging k-offset (elements)

#define STAGE2(BUFOFF, K0)                                                         \
  {                                                                                \
    const bf16* gx = Xbf + ((size_t)b * Sn + w * 128 + rr2) * Hn + (K0) + cc2;     \
    char* dx = sm + (BUFOFF) + (w * 128) * 64;                                     \
    _Pragma("unroll")                                                              \
    for (int i = 0; i < 8; ++i) {                                                  \
      gld_lds16(gx, dx);                                                           \
      gx += 16 * Hn;                                                               \
      dx += 16 * 64;                                                               \
    }                                                                              \
    const bf16* gw = Wbf + ((size_t)(l0 + w * 16 + rr2)) * Hn + (K0) + cc2;        \
    gld_lds16(gw, sm + (BUFOFF) + WS_OFF_IN + (w * 16) * 64);                      \
  }

#define PH2_COMPUTE(BUFOFF)                                                        \
  {                                                                                \
    const char* xs = sm + (BUFOFF);                                                \
    const char* ws = sm + (BUFOFF) + WS_OFF_IN;                                    \
    bf16x8 aF[4], bF[8];                                                           \
    _Pragma("unroll")                                                              \
    for (int am = 0; am < 4; ++am)                                                 \
      aF[am] = *(const bf16x8*)&ws[(am * 16 + col) * 64 + quad * 16];              \
    _Pragma("unroll")                                                              \
    for (int nt = 0; nt < 8; ++nt)                                                 \
      bF[nt] = *(const bf16x8*)&xs[(w * 128 + nt * 16 + col) * 64 + quad * 16];    \
    _Pragma("unroll")                                                              \
    for (int nt = 0; nt < 8; ++nt)                                                 \
      _Pragma("unroll")                                                            \
      for (int am = 0; am < 4; ++am)                                               \
        acc[am][nt] = __builtin_amdgcn_mfma_f32_16x16x32_bf16(aF[am], bF[nt], acc[am][nt], 0, 0, 0); \
  }

  STAGE2(0, 0);
  asm volatile("s_waitcnt vmcnt(0)" ::: "memory");
  __builtin_amdgcn_s_barrier();
  for (int k0 = 0; k0 < Hn; k0 += 64) {
    STAGE2(PH2_BUF, k0 + 32);
    PH2_COMPUTE(0);
    asm volatile("s_waitcnt vmcnt(0)" ::: "memory");
    __builtin_amdgcn_s_barrier();
    if (k0 + 64 < Hn) STAGE2(0, k0 + 64);
    PH2_COMPUTE(PH2_BUF);
    asm volatile("s_waitcnt vmcnt(0)" ::: "memory");
    __builtin_amdgcn_s_barrier();
  }
#undef STAGE2
#undef PH2_COMPUTE

  // ---- phase 3: masked softmax, 4-way cross-wave combine over s-slices ----
  float* redm = (float*)&sm[REDM_OFF];
  float* reds = (float*)&sm[REDS_OFF];
  float mx[4][4];
#pragma unroll
  for (int am = 0; am < 4; ++am)
#pragma unroll
    for (int r = 0; r < 4; ++r) mx[am][r] = -3e38f;
#pragma unroll
  for (int am = 0; am < 4; ++am)
#pragma unroll
    for (int nt = 0; nt < 8; ++nt)
#pragma unroll
      for (int r = 0; r < 4; ++r) {
        acc[am][nt][r] += bias_r[nt];
        mx[am][r] = fmaxf(mx[am][r], acc[am][nt][r]);
      }
#pragma unroll
  for (int am = 0; am < 4; ++am)
#pragma unroll
    for (int r = 0; r < 4; ++r) {
      mx[am][r] = fmaxf(mx[am][r], __shfl_xor(mx[am][r], 1, 64));
      mx[am][r] = fmaxf(mx[am][r], __shfl_xor(mx[am][r], 2, 64));
      mx[am][r] = fmaxf(mx[am][r], __shfl_xor(mx[am][r], 4, 64));
      mx[am][r] = fmaxf(mx[am][r], __shfl_xor(mx[am][r], 8, 64));
    }
  if (col == 0) {
#pragma unroll
    for (int am = 0; am < 4; ++am)
#pragma unroll
      for (int r = 0; r < 4; ++r)
        redm[w * 64 + am * 16 + quad * 4 + r] = mx[am][r];
  }
  __syncthreads();
  float gmax[4][4], sum[4][4];
#pragma unroll
  for (int am = 0; am < 4; ++am)
#pragma unroll
    for (int r = 0; r < 4; ++r) {
      const int row = am * 16 + quad * 4 + r;
      gmax[am][r] = fmaxf(fmaxf(redm[row], redm[64 + row]),
                          fmaxf(redm[128 + row], redm[192 + row]));
      sum[am][r] = 0.f;
    }
#pragma unroll
  for (int am = 0; am < 4; ++am)
#pragma unroll
    for (int nt = 0; nt < 8; ++nt)
#pragma unroll
      for (int r = 0; r < 4; ++r) {
        const float e = __expf(acc[am][nt][r] - gmax[am][r]);
        acc[am][nt][r] = e;
        sum[am][r] += e;
      }
#pragma unroll
  for (int am = 0; am < 4; ++am)
#pragma unroll
    for (int r = 0; r < 4; ++r) {
      sum[am][r] += __shfl_xor(sum[am][r], 1, 64);
      sum[am][r] += __shfl_xor(sum[am][r], 2, 64);
      sum[am][r] += __shfl_xor(sum[am][r], 4, 64);
      sum[am][r] += __shfl_xor(sum[am][r], 8, 64);
    }
  if (col == 0) {
#pragma unroll
    for (int am = 0; am < 4; ++am)
#pragma unroll
      for (int r = 0; r < 4; ++r)
        reds[w * 64 + am * 16 + quad * 4 + r] = sum[am][r];
  }
  __syncthreads();
  float rs[4][4];
#pragma unroll
  for (int am = 0; am < 4; ++am)
#pragma unroll
    for (int r = 0; r < 4; ++r) {
      const int row = am * 16 + quad * 4 + r;
      rs[am][r] = 1.0f / (reds[row] + reds[64 + row] + reds[128 + row] + reds[192 + row]);
    }

  // ---- phase 4: P (unnormalized exp) -> LDS bf16, b32 packed via shfl pairing ----
  // P row = 1024 B (512 bf16). 16B chunk c of row stored at slot c ^ (row&7).
  const int pi = col & 1;  // parity
#pragma unroll
  for (int am = 0; am < 4; ++am)
#pragma unroll
    for (int t = 0; t < 4; ++t)
#pragma unroll
      for (int r = 0; r < 4; ++r) {
        const float own0 = acc[am][2 * t][r];
        const float own1 = acc[am][2 * t + 1][r];
        const float p0 = __shfl_xor(own0, 1, 64);
        const float p1 = __shfl_xor(own1, 1, 64);
        const float lo = pi ? p1 : own0;
        const float hi = pi ? own1 : p0;
        const unsigned pk = (unsigned)bfbits(lo) | ((unsigned)bfbits(hi) << 16);
        const int nt_w = 2 * t + pi;
        const int row = am * 16 + quad * 4 + r;
        const int sp = w * 128 + nt_w * 16 + (col & ~1);
        const int slot = (sp >> 3) ^ (row & 7);
        *(unsigned*)&sm[P_OFF + row * 1024 + slot * 16 + (sp & 7) * 2] = pk;
      }

  __syncthreads();  // P fully written, visible to all waves

  // ---- phase 5 pre: hoist this wave's P fragments to registers (read ONCE) ----
  // A-frag for (a, kf): rows lg*32+a*16..+15, s = kf*32 + quad*8 + 0..7
  bf16x8 preg[2][16];
#pragma unroll
  for (int a = 0; a < 2; ++a) {
    const int row = lg * 32 + a * 16 + col;
#pragma unroll
    for (int kf = 0; kf < 16; ++kf) {
      const int slot = (kf * 4 + quad) ^ (row & 7);
      preg[a][kf] = *(const bf16x8*)&sm[P_OFF + row * 1024 + slot * 16];
    }
  }
  __syncthreads();  // all hoists complete; P region now free for XT dbuf

  // ---- phase 5: O[64l x 768h] = P(regs) x XT(LDS dbuf @0/@16384) ----
  const int rr5 = lane >> 3;
  const int cc5 = lane & 7;
  auto stage_xt = [&](int bufoff, int n0, int s0) {
    // chunk swizzle at the SOURCE: lane (rr,cc) fetches s-chunk cc^rr so that
    // row rr's chunk c lands at LDS slot c^rr.
    const int r0 = w * 32;
    const bf16* g = XTg + ((size_t)b * Hn + n0 * 128 + r0 + rr5) * Sn + s0 + (cc5 ^ rr5) * 8;
#pragma unroll
    for (int i = 0; i < 4; ++i) {
      gld_lds16(g, &sm[bufoff + (r0 + i * 8) * 128]);
      g += 8 * Sn;
    }
  };

  stage_xt(0, 0, 0);
  asm volatile("s_waitcnt vmcnt(0)" ::: "memory");
  __builtin_amdgcn_s_barrier();

  for (int n0 = 0; n0 < Hn / 128; ++n0) {
    f32x4 oacc[2][4];
#pragma unroll
    for (int a = 0; a < 2; ++a)
#pragma unroll
      for (int nt = 0; nt < 4; ++nt) oacc[a][nt] = zero;
#pragma unroll
    for (int s0i = 0; s0i < 8; ++s0i) {
      const int par = s0i & 1;
      // prefetch next tile into the other buffer BEFORE compute (hidden by MFMAs)
      if (s0i < 7)           stage_xt((par ^ 1) * 16384, n0, (s0i + 1) * 64);
      else if (n0 < Hn / 128 - 1) stage_xt((par ^ 1) * 16384, n0 + 1, 0);
#pragma unroll
      for (int ks = 0; ks < 2; ++ks) {
        const int kf = s0i * 2 + ks;
        const bf16x8 pa0 = preg[0][kf];
        const bf16x8 pa1 = preg[1][kf];
#pragma unroll
        for (int nt = 0; nt < 4; ++nt) {
          const int hl = (nt * 2 + sg) * 16 + col;
          const int xslot = (ks * 4 + quad) ^ (hl & 7);
          bf16x8 xb = *(const bf16x8*)&sm[par * 16384 + hl * 128 + xslot * 16];
          oacc[0][nt] = __builtin_amdgcn_mfma_f32_16x16x32_bf16(pa0, xb, oacc[0][nt], 0, 0, 0);
          oacc[1][nt] = __builtin_amdgcn_mfma_f32_16x16x32_bf16(pa1, xb, oacc[1][nt], 0, 0, 0);
        }
      }
      asm volatile("s_waitcnt vmcnt(0)" ::: "memory");  // prefetch (issued pre-compute) landed
      __builtin_amdgcn_s_barrier();                     // next buffer published
    }
#pragma unroll
    for (int a = 0; a < 2; ++a)
#pragma unroll
      for (int nt = 0; nt < 4; ++nt) {
        const int h = n0 * 128 + (nt * 2 + sg) * 16 + col;
        const int lbase = l0 + lg * 32 + a * 16 + quad * 4;
#pragma unroll
        for (int r = 0; r < 4; ++r)
          out[((size_t)b * Ln + lbase + r) * Hn + h] = oacc[a][nt][r] * rs[lg * 2 + a][r];
      }
  }
}

// ---- fallback (ws too small): fp32 wave-per-(b,l), slow but correct ----
__global__ __launch_bounds__(256) void attn_fallback_kernel(
    const float* __restrict__ X, const int* __restrict__ masks,
    const float* __restrict__ W, float* __restrict__ out) {
  __shared__ float sc[4][Sn];
  const int wv = threadIdx.x >> 6, lane = threadIdx.x & 63;
  const int gw = blockIdx.x * 4 + wv;
  const int b = gw / Ln, l = gw % Ln;
  float wreg[12];
#pragma unroll
  for (int j = 0; j < 12; ++j) wreg[j] = W[(size_t)l * Hn + j * 64 + lane];
  for (int s = 0; s < Sn; ++s) {
    const float* xr = X + ((size_t)b * Sn + s) * Hn;
    float p = 0.f;
#pragma unroll
    for (int j = 0; j < 12; ++j) p += xr[j * 64 + lane] * wreg[j];
#pragma unroll
    for (int off = 32; off > 0; off >>= 1) p += __shfl_xor(p, off, 64);
    if (lane == 0) sc[wv][s] = p;
  }
  __syncthreads();
  float m = -3e38f;
#pragma unroll
  for (int i = 0; i < 8; ++i) {
    const int s = lane * 8 + i;
    const float v = sc[wv][s] + (masks[b * Sn + s] ? 0.f : -1e30f);
    sc[wv][s] = v;
    m = fmaxf(m, v);
  }
#pragma unroll
  for (int off = 32; off > 0; off >>= 1) m = fmaxf(m, __shfl_xor(m, off, 64));
  __syncthreads();
  float sum = 0.f;
#pragma unroll
  for (int i = 0; i < 8; ++i) {
    const int s = lane * 8 + i;
    const float e = __expf(sc[wv][s] - m);
    sc[wv][s] = e;
    sum += e;
  }
#pragma unroll
  for (int off = 32; off > 0; off >>= 1) sum += __shfl_xor(sum, off, 64);
  const float rs = 1.0f / sum;
  __syncthreads();
  float o[12];
#pragma unroll
  for (int j = 0; j < 12; ++j) o[j] = 0.f;
  for (int s = 0; s < Sn; ++s) {
    const float p = sc[wv][s];
    const float* xr = X + ((size_t)b * Sn + s) * Hn;
#pragma unroll
    for (int j = 0; j < 12; ++j) o[j] += p * xr[j * 64 + lane];
  }
#pragma unroll
  for (int j = 0; j < 12; ++j)
    out[((size_t)b * Ln + l) * Hn + j * 64 + lane] = o[j] * rs;
}

extern "C" void kernel_launch(void* const* d_in, const int* in_sizes, int n_in,
                              void* d_out, int out_size, void* d_ws, size_t ws_size,
                              hipStream_t stream) {
  const float* X     = (const float*)d_in[0];
  const int*   masks = (const int*)d_in[1];
  const float* W     = (const float*)d_in[2];
  float* out = (float*)d_out;

  const size_t need = ((size_t)2 * Bn * Sn * Hn + (size_t)Ln * Hn) * sizeof(bf16);
  if (ws_size >= need) {
    bf16* Xbf = (bf16*)d_ws;
    bf16* XT  = Xbf + (size_t)Bn * Sn * Hn;
    bf16* Wbf = XT  + (size_t)Bn * Sn * Hn;
    convert_x_kernel<<<dim3(Hn / 64, Sn / 64, Bn), 256, 0, stream>>>(X, Xbf, XT);
    convert_w_kernel<<<dim3((Ln * Hn) / 2048), 256, 0, stream>>>(W, Wbf);
    attn_main_kernel<<<dim3(Bn * (Ln / BL)), 256, 0, stream>>>(masks, Xbf, XT, Wbf, out);
  } else {
    attn_fallback_kernel<<<dim3(Bn * Ln / 4), 256, 0, stream>>>(X, masks, W, out);
  }
}